// Round 1
// baseline (939.935 us; speedup 1.0000x reference)
//
#include <hip/hip_runtime.h>
#include <hip/hip_bf16.h>
#include <cstdint>
#include <cstddef>

// GCN on MI355X: out = A@(A@(relu(A@(X W1^T)) ... )) using associativity:
//   relu((A@H)@W^T) == relu(A@(H@W^T))
// so each layer = tiny projection P = H@W^T (transposed, bf16) + one
// HBM-bound tall-skinny MFMA GEMM relu(A@P).
// Layer 1 reads fp32 A and saves a bf16 copy to d_ws (if it fits);
// layers 2-3 stream the bf16 copy (halves their traffic).

#define NN 16384
#define SPLITK 4
#define KCHUNK (NN / SPLITK)

typedef __attribute__((ext_vector_type(8))) short s16x8;
typedef __attribute__((ext_vector_type(4))) float fx4;

// round-to-nearest-even f32 -> bf16 (manual, avoids any __bf16 ABI surprises)
__device__ __forceinline__ unsigned short f2bf_rne(float f) {
    unsigned int x = __builtin_bit_cast(unsigned int, f);
    x += 0x7fffu + ((x >> 16) & 1u);
    return (unsigned short)(x >> 16);
}

// ---------------------------------------------------------------------------
// Big GEMM: part[s] = A[:, kchunk_s] @ P[kchunk_s, :]   (per split-K slice)
// A-frag (16x16x32 bf16 MFMA): row = lane&15, 8 contiguous k per lane at
// k = (lane>>4)*8. B from PT[D][NN] (P transposed) -> 16B contiguous per lane.
// No LDS, no syncthreads: each wave owns 16 rows x all D cols.
// AMODE: 0 = read fp32 A, 1 = read fp32 A + save bf16 copy, 2 = read bf16 A.
// ---------------------------------------------------------------------------
template <int D, int AMODE>
__global__ __launch_bounds__(256, 4) void k_spmm(
    const float* __restrict__ A32,
    const unsigned short* __restrict__ Abf_r,
    unsigned short* __restrict__ Abf_w,
    const unsigned short* __restrict__ PT,   // [D][NN] bf16
    float* __restrict__ part)                // [SPLITK][NN][D] f32
{
    const int lane = threadIdx.x & 63;
    const int wv   = threadIdx.x >> 6;
    const int srow = lane & 15;
    const int kg   = lane >> 4;           // 0..3
    const int row  = blockIdx.x * 64 + wv * 16 + srow;
    const int s    = blockIdx.y;
    const long kbeg = (long)s * KCHUNK;

    fx4 acc[D / 16];
#pragma unroll
    for (int c = 0; c < D / 16; ++c) acc[c] = (fx4){0.f, 0.f, 0.f, 0.f};

    const long abase = (long)row * NN + kbeg + kg * 8;

#pragma unroll 2
    for (int i = 0; i < KCHUNK / 32; ++i) {
        const long aoff = abase + (long)i * 32;
        s16x8 af;
        if (AMODE == 2) {
            af = *(const s16x8*)(Abf_r + aoff);
        } else {
            fx4 a0 = *(const fx4*)(A32 + aoff);
            fx4 a1 = *(const fx4*)(A32 + aoff + 4);
            s16x8 t;
            t[0] = (short)f2bf_rne(a0[0]);
            t[1] = (short)f2bf_rne(a0[1]);
            t[2] = (short)f2bf_rne(a0[2]);
            t[3] = (short)f2bf_rne(a0[3]);
            t[4] = (short)f2bf_rne(a1[0]);
            t[5] = (short)f2bf_rne(a1[1]);
            t[6] = (short)f2bf_rne(a1[2]);
            t[7] = (short)f2bf_rne(a1[3]);
            af = t;
            if (AMODE == 1) *(s16x8*)(Abf_w + aoff) = af;
        }
        const long koff = kbeg + (long)i * 32 + kg * 8;
#pragma unroll
        for (int c = 0; c < D / 16; ++c) {
            s16x8 bf = *(const s16x8*)(PT + (long)(c * 16 + srow) * NN + koff);
            acc[c] = __builtin_amdgcn_mfma_f32_16x16x32_bf16(af, bf, acc[c], 0, 0, 0);
        }
    }

    // C layout (m89-verified): col = lane&15, row = (lane>>4)*4 + reg
    float* pbase = part + (long)s * NN * D;
    const int orow = blockIdx.x * 64 + wv * 16 + kg * 4;
#pragma unroll
    for (int c = 0; c < D / 16; ++c)
#pragma unroll
        for (int r = 0; r < 4; ++r)
            pbase[(long)(orow + r) * D + c * 16 + srow] = acc[c][r];
}

// ---------------------------------------------------------------------------
// Projection: PT[c][r] = bf16( act(H[r,:]) @ W[c,:] )
// H = (NSUM==1) ? src : relu(sum_s partials[s])   (relu iff RELU)
// 64 rows per block, W and H staged in LDS.
// ---------------------------------------------------------------------------
template <int DIN, int DOUT, int NSUM, bool RELU>
__global__ __launch_bounds__(256) void k_proj(
    const float* __restrict__ src,     // [NSUM][NN][DIN]
    const float* __restrict__ W,       // [DOUT][DIN]
    unsigned short* __restrict__ PT)   // [DOUT][NN]
{
    __shared__ float Ws[DOUT * DIN];
    __shared__ float Hs[64][DIN + 1];
    const int tid = threadIdx.x;
    for (int i = tid; i < DOUT * DIN; i += 256) Ws[i] = W[i];
    const int rbase = blockIdx.x * 64;
    for (int i = tid; i < 64 * DIN; i += 256) {
        const int rl = i / DIN, k = i % DIN;
        float v = 0.f;
#pragma unroll
        for (int s2 = 0; s2 < NSUM; ++s2)
            v += src[(long)s2 * NN * DIN + (long)(rbase + rl) * DIN + k];
        Hs[rl][k] = RELU ? fmaxf(v, 0.f) : v;
    }
    __syncthreads();
    const int rl = tid & 63;
    const int c0 = tid >> 6;
    for (int c = c0; c < DOUT; c += 4) {
        float accv = 0.f;
#pragma unroll
        for (int k = 0; k < DIN; ++k) accv += Hs[rl][k] * Ws[c * DIN + k];
        PT[(long)c * NN + rbase + rl] = f2bf_rne(accv);
    }
}

// Final reduce: out[NN][32] = sum_s part[s]  (fp32, no activation)
__global__ __launch_bounds__(256) void k_red(
    const float* __restrict__ part, float* __restrict__ out)
{
    const int e = blockIdx.x * 256 + threadIdx.x;   // f32x4 index
    if (e >= NN * 32 / 4) return;
    fx4 v = (fx4){0.f, 0.f, 0.f, 0.f};
#pragma unroll
    for (int s = 0; s < SPLITK; ++s)
        v += *(const fx4*)(part + (long)s * NN * 32 + (long)e * 4);
    *(fx4*)(out + (long)e * 4) = v;
}

extern "C" void kernel_launch(void* const* d_in, const int* in_sizes, int n_in,
                              void* d_out, int out_size, void* d_ws, size_t ws_size,
                              hipStream_t stream) {
    const float* A  = (const float*)d_in[0];
    const float* X  = (const float*)d_in[1];
    const float* W1 = (const float*)d_in[2];
    const float* W2 = (const float*)d_in[3];
    const float* W3 = (const float*)d_in[4];
    float* out = (float*)d_out;

    char* ws = (char*)d_ws;
    const size_t part_b = (size_t)SPLITK * NN * 64 * 4;  // 16 MiB
    const size_t pt_b   = (size_t)64 * NN * 2;           //  2 MiB
    const size_t abf_b  = (size_t)NN * NN * 2;           // 512 MiB
    float*          part = (float*)ws;
    unsigned short* PT   = (unsigned short*)(ws + part_b);
    unsigned short* Abf  = (unsigned short*)(ws + part_b + pt_b);
    const bool save = ws_size >= part_b + pt_b + abf_b;

    dim3 b(256);
    dim3 gP(NN / 64);
    dim3 gG(NN / 64, SPLITK);

    // Layer 1: PT = (X @ W1^T)^T ; part = split-K A@P (save bf16 A copy)
    k_proj<64, 64, 1, false><<<gP, b, 0, stream>>>(X, W1, PT);
    if (save) k_spmm<64, 1><<<gG, b, 0, stream>>>(A, nullptr, Abf, PT, part);
    else      k_spmm<64, 0><<<gG, b, 0, stream>>>(A, nullptr, nullptr, PT, part);

    // Layer 2: PT = (relu(sum part) @ W2^T)^T ; part = A@P
    k_proj<64, 32, SPLITK, true><<<gP, b, 0, stream>>>(part, W2, PT);
    if (save) k_spmm<32, 2><<<gG, b, 0, stream>>>(nullptr, Abf, nullptr, PT, part);
    else      k_spmm<32, 0><<<gG, b, 0, stream>>>(A, nullptr, nullptr, PT, part);

    // Layer 3: PT = (relu(sum part) @ W3^T)^T ; part = A@P
    k_proj<32, 32, SPLITK, true><<<gP, b, 0, stream>>>(part, W3, PT);
    if (save) k_spmm<32, 2><<<gG, b, 0, stream>>>(nullptr, Abf, nullptr, PT, part);
    else      k_spmm<32, 0><<<gG, b, 0, stream>>>(A, nullptr, nullptr, PT, part);

    // out = sum part (fp32, no relu)
    k_red<<<dim3(NN * 32 / 4 / 256), b, 0, stream>>>(part, out);
}

// Round 2
// 821.514 us; speedup vs baseline: 1.1441x; 1.1441x over previous
//
#include <hip/hip_runtime.h>
#include <cstdint>
#include <cstddef>

// GCN via associativity: relu((A@H)@W^T) == relu(A@(H@W^T)).
// Each layer = tiny projection PT = (H@W^T)^T (bf16, k-slot-permuted) +
// one HBM-bound tall-skinny MFMA GEMM part = A@P (split-K).
// Layer 1 streams fp32 A (dense 64B-per-row-per-instr loads via the slot
// permutation), saves a bf16 slot-ordered copy; layers 2-3 stream the copy.
//
// Slot permutation (A and B must agree; bijection cancels in the MFMA dot):
//   lane kg = lane>>4 holds slots 0..7 = logical k {kg*4..kg*4+3, 16+kg*4..+3}
//   within each 32-k group. Stored position p(k) = ((k&15)>>2)*8 + (k&3) + ((k>>4)<<2).

#define NN 16384
#define SPLITK 8
#define KCHUNK (NN / SPLITK)   // 2048

typedef __attribute__((ext_vector_type(8))) short s16x8;
typedef __attribute__((ext_vector_type(4))) float fx4;

__device__ __forceinline__ unsigned short f2bf_rne(float f) {
    unsigned int x = __builtin_bit_cast(unsigned int, f);
    x += 0x7fffu + ((x >> 16) & 1u);
    return (unsigned short)(x >> 16);
}

__device__ __forceinline__ s16x8 pack_bf(fx4 a, fx4 b) {
    s16x8 t;
    t[0] = (short)f2bf_rne(a[0]);
    t[1] = (short)f2bf_rne(a[1]);
    t[2] = (short)f2bf_rne(a[2]);
    t[3] = (short)f2bf_rne(a[3]);
    t[4] = (short)f2bf_rne(b[0]);
    t[5] = (short)f2bf_rne(b[1]);
    t[6] = (short)f2bf_rne(b[2]);
    t[7] = (short)f2bf_rne(b[3]);
    return t;
}

// ---------------------------------------------------------------------------
// part[s] = A[:, kchunk_s] @ P[kchunk_s, :]
// Per wave: 2 row-tiles (32 rows) x all D cols; B-frags shared across tiles.
// AMODE: 0 = read fp32 A; 1 = fp32 A + save bf16 slot-ordered copy; 2 = bf16 A.
// ---------------------------------------------------------------------------
template <int D, int AMODE>
__global__ __launch_bounds__(256, 4) void k_spmm(
    const float* __restrict__ A32,
    const unsigned short* __restrict__ Abf_r,
    unsigned short* __restrict__ Abf_w,
    const unsigned short* __restrict__ PT,   // [D][NN] bf16, slot-permuted
    float* __restrict__ part)                // [SPLITK][NN][D] f32
{
    const int lane = threadIdx.x & 63;
    const int wv   = threadIdx.x >> 6;
    const int srow = lane & 15;
    const int kg   = lane >> 4;              // 0..3
    const int s    = blockIdx.y;
    const long kbeg = (long)s * KCHUNK;
    const int rowbase = blockIdx.x * 128 + wv * 32;
    const long r0 = rowbase + srow;
    const long r1 = rowbase + 16 + srow;

    fx4 acc0[D / 16], acc1[D / 16];
#pragma unroll
    for (int c = 0; c < D / 16; ++c) {
        acc0[c] = (fx4){0.f, 0.f, 0.f, 0.f};
        acc1[c] = (fx4){0.f, 0.f, 0.f, 0.f};
    }

#pragma unroll 2
    for (int i = 0; i < KCHUNK / 32; ++i) {
        const long ko = kbeg + (long)i * 32;
        s16x8 af0, af1;
        if (AMODE == 2) {
            af0 = __builtin_nontemporal_load((const s16x8*)(Abf_r + r0 * (long)NN + ko + kg * 8));
            af1 = __builtin_nontemporal_load((const s16x8*)(Abf_r + r1 * (long)NN + ko + kg * 8));
        } else {
            const float* p0 = A32 + r0 * (long)NN + ko + kg * 4;
            const float* p1 = A32 + r1 * (long)NN + ko + kg * 4;
            fx4 a00 = __builtin_nontemporal_load((const fx4*)p0);
            fx4 a01 = __builtin_nontemporal_load((const fx4*)(p0 + 16));
            fx4 a10 = __builtin_nontemporal_load((const fx4*)p1);
            fx4 a11 = __builtin_nontemporal_load((const fx4*)(p1 + 16));
            af0 = pack_bf(a00, a01);
            af1 = pack_bf(a10, a11);
            if (AMODE == 1) {
                __builtin_nontemporal_store(af0, (s16x8*)(Abf_w + r0 * (long)NN + ko + kg * 8));
                __builtin_nontemporal_store(af1, (s16x8*)(Abf_w + r1 * (long)NN + ko + kg * 8));
            }
        }
#pragma unroll
        for (int c = 0; c < D / 16; ++c) {
            s16x8 bf = *(const s16x8*)(PT + (long)(c * 16 + srow) * NN + ko + kg * 8);
            acc0[c] = __builtin_amdgcn_mfma_f32_16x16x32_bf16(af0, bf, acc0[c], 0, 0, 0);
            acc1[c] = __builtin_amdgcn_mfma_f32_16x16x32_bf16(af1, bf, acc1[c], 0, 0, 0);
        }
    }

    // C layout (m89-verified): col = lane&15, row = (lane>>4)*4 + reg
    float* pbase = part + (long)s * NN * D;
#pragma unroll
    for (int c = 0; c < D / 16; ++c) {
#pragma unroll
        for (int r = 0; r < 4; ++r) {
            pbase[(long)(rowbase + kg * 4 + r) * D + c * 16 + srow]      = acc0[c][r];
            pbase[(long)(rowbase + 16 + kg * 4 + r) * D + c * 16 + srow] = acc1[c][r];
        }
    }
}

// ---------------------------------------------------------------------------
// Projection: PT[c][perm(r)] = bf16( act(H[r,:]) @ W[c,:] )
// H = (NSUM==1) ? src : relu(sum_s partials[s])   (relu iff RELU)
// ---------------------------------------------------------------------------
template <int DIN, int DOUT, int NSUM, bool RELU>
__global__ __launch_bounds__(256) void k_proj(
    const float* __restrict__ src,     // [NSUM][NN][DIN]
    const float* __restrict__ W,       // [DOUT][DIN]
    unsigned short* __restrict__ PT)   // [DOUT][NN] slot-permuted
{
    __shared__ float Ws[DOUT * DIN];
    __shared__ float Hs[64][DIN + 1];
    const int tid = threadIdx.x;
    for (int i = tid; i < DOUT * DIN; i += 256) Ws[i] = W[i];
    const int rbase = blockIdx.x * 64;
    for (int i = tid; i < 64 * DIN; i += 256) {
        const int rl = i / DIN, k = i % DIN;
        float v = 0.f;
#pragma unroll
        for (int s2 = 0; s2 < NSUM; ++s2)
            v += src[(long)s2 * NN * DIN + (long)(rbase + rl) * DIN + k];
        Hs[rl][k] = RELU ? fmaxf(v, 0.f) : v;
    }
    __syncthreads();
    const int rl = tid & 63;
    const int c0 = tid >> 6;
    const int r  = rbase + rl;
    const int kk = r & 31;
    const int pidx = (r & ~31) + ((kk & 15) >> 2) * 8 + (kk & 3) + ((kk >> 4) << 2);
    for (int c = c0; c < DOUT; c += 4) {
        float accv = 0.f;
#pragma unroll
        for (int k = 0; k < DIN; ++k) accv += Hs[rl][k] * Ws[c * DIN + k];
        PT[(long)c * NN + pidx] = f2bf_rne(accv);
    }
}

// Final reduce: out[NN][32] = sum_s part[s]  (fp32, no activation)
__global__ __launch_bounds__(256) void k_red(
    const float* __restrict__ part, float* __restrict__ out)
{
    const int e = blockIdx.x * 256 + threadIdx.x;   // f32x4 index
    if (e >= NN * 32 / 4) return;
    fx4 v = (fx4){0.f, 0.f, 0.f, 0.f};
#pragma unroll
    for (int s = 0; s < SPLITK; ++s)
        v += __builtin_nontemporal_load((const fx4*)(part + (long)s * NN * 32 + (long)e * 4));
    *(fx4*)(out + (long)e * 4) = v;
}

extern "C" void kernel_launch(void* const* d_in, const int* in_sizes, int n_in,
                              void* d_out, int out_size, void* d_ws, size_t ws_size,
                              hipStream_t stream) {
    const float* A  = (const float*)d_in[0];
    const float* X  = (const float*)d_in[1];
    const float* W1 = (const float*)d_in[2];
    const float* W2 = (const float*)d_in[3];
    const float* W3 = (const float*)d_in[4];
    float* out = (float*)d_out;

    char* ws = (char*)d_ws;
    const size_t part_b = (size_t)SPLITK * NN * 64 * 4;  // 32 MiB
    const size_t pt_b   = (size_t)64 * NN * 2;           //  2 MiB
    const size_t abf_b  = (size_t)NN * NN * 2;           // 512 MiB
    float*          part = (float*)ws;
    unsigned short* PT   = (unsigned short*)(ws + part_b);
    unsigned short* Abf  = (unsigned short*)(ws + part_b + pt_b);
    const bool save = ws_size >= part_b + pt_b + abf_b;

    dim3 b(256);
    dim3 gP(NN / 64);
    dim3 gG(NN / 128, SPLITK);

    // Layer 1
    k_proj<64, 64, 1, false><<<gP, b, 0, stream>>>(X, W1, PT);
    if (save) k_spmm<64, 1><<<gG, b, 0, stream>>>(A, nullptr, Abf, PT, part);
    else      k_spmm<64, 0><<<gG, b, 0, stream>>>(A, nullptr, nullptr, PT, part);

    // Layer 2
    k_proj<64, 32, SPLITK, true><<<gP, b, 0, stream>>>(part, W2, PT);
    if (save) k_spmm<32, 2><<<gG, b, 0, stream>>>(nullptr, Abf, nullptr, PT, part);
    else      k_spmm<32, 0><<<gG, b, 0, stream>>>(A, nullptr, nullptr, PT, part);

    // Layer 3
    k_proj<32, 32, SPLITK, true><<<gP, b, 0, stream>>>(part, W3, PT);
    if (save) k_spmm<32, 2><<<gG, b, 0, stream>>>(nullptr, Abf, nullptr, PT, part);
    else      k_spmm<32, 0><<<gG, b, 0, stream>>>(A, nullptr, nullptr, PT, part);

    k_red<<<dim3(NN * 32 / 4 / 256), b, 0, stream>>>(part, out);
}